// Round 11
// baseline (362.904 us; speedup 1.0000x reference)
//
#include <hip/hip_runtime.h>
#include <cstdint>

#define N_NODES 100000
#define N_EDGES 1600000

constexpr int NCB = 196;   // coarse buckets: dst >> 9 (512 nodes each)
constexpr int HB  = 391;   // binning blocks, 4096 edges each
constexpr int NBK = N_NODES / 4; // 25000 agg blocks (4 nodes/block)

typedef __attribute__((ext_vector_type(8))) short short8;
typedef __attribute__((ext_vector_type(4))) float f32x4;

__device__ inline uint32_t fbits(float f) { union { float f; uint32_t u; } c; c.f = f; return c.u; }
__device__ inline float bfloat(uint32_t u) { union { uint32_t u; float f; } c; c.u = u; return c.f; }

__device__ inline void bsplit(float a, short& hi, short& lo) {
    uint32_t h = fbits(a) & 0xFFFF0000u;
    float fl = a - bfloat(h);
    hi = (short)(h >> 16);
    lo = (short)(fbits(fl) >> 16);
}

__device__ inline ushort f2bf(float f) { // RNE fp32->bf16
    uint32_t u = fbits(f);
    return (ushort)((u + 0x7FFFu + ((u >> 16) & 1u)) >> 16);
}

// bf16-pair accumulate (proven unpack path; fdot2 experiment reverted — its
// operand type on this ROCm is v2i16, so bf16 "1.0" constants became denormals)
__device__ inline void acc_word(uint32_t w, float& lo, float& hi) {
    lo += bfloat(w << 16);
    hi += bfloat(w & 0xFFFF0000u);
}

// ---------------- binning: hist -> scan/bases -> scatter ----------------

__global__ __launch_bounds__(256)
void hist_kernel(const int* __restrict__ dst, int* __restrict__ H) {
    __shared__ int h[NCB];
    for (int i = threadIdx.x; i < NCB; i += 256) h[i] = 0;
    __syncthreads();
    int e0 = blockIdx.x * 4096;
    #pragma unroll
    for (int it = 0; it < 16; ++it) {
        int e = e0 + it * 256 + threadIdx.x;
        if (e < N_EDGES) atomicAdd(&h[dst[e] >> 9], 1);
    }
    __syncthreads();
    for (int i = threadIdx.x; i < NCB; i += 256) H[blockIdx.x * NCB + i] = h[i];
}

__global__ __launch_bounds__(256)
void scanbase_kernel(int* __restrict__ H, int* __restrict__ boff) {
    __shared__ int tot[NCB];
    __shared__ int base[NCB + 1];
    int j = threadIdx.x;
    if (j < NCB) {
        int s = 0;
        for (int b = 0; b < HB; ++b) s += H[b * NCB + j];
        tot[j] = s;
    }
    __syncthreads();
    if (j == 0) {
        int run = 0;
        for (int k = 0; k < NCB; ++k) { base[k] = run; run += tot[k]; }
        base[NCB] = run;
    }
    __syncthreads();
    if (j <= NCB) boff[j] = base[j];
    if (j < NCB) {
        int run = base[j];
        for (int b = 0; b < HB; ++b) {
            int v = H[b * NCB + j];
            H[b * NCB + j] = run;
            run += v;
        }
    }
}

__global__ __launch_bounds__(256)
void scatter_kernel(const int* __restrict__ src, const int* __restrict__ dst,
                    const int* __restrict__ H, uint32_t* __restrict__ ebuf) {
    __shared__ int cur[NCB];
    for (int i = threadIdx.x; i < NCB; i += 256) cur[i] = H[blockIdx.x * NCB + i];
    __syncthreads();
    int e0 = blockIdx.x * 4096;
    #pragma unroll
    for (int it = 0; it < 16; ++it) {
        int e = e0 + it * 256 + threadIdx.x;
        if (e < N_EDGES) {
            int d = dst[e];
            int p = atomicAdd(&cur[d >> 9], 1);
            ebuf[p] = ((uint32_t)src[e] << 9) | (uint32_t)(d & 511);
        }
    }
}

// ---------------- bucket -> exact CSR ----------------

__global__ __launch_bounds__(256)
void bucket_csr(const uint32_t* __restrict__ ebuf, const int* __restrict__ boff,
                int* __restrict__ off, float* __restrict__ dinv,
                int* __restrict__ ssrc) {
    __shared__ int deg[512];
    __shared__ int cur[512];
    __shared__ int wsum[4];
    int t = threadIdx.x, lane = t & 63, w = t >> 6;
    int j = blockIdx.x;
    int base = boff[j], end = boff[j + 1];
    int node0 = j << 9;

    deg[t] = 0; deg[t + 256] = 0;
    __syncthreads();

    for (int p = base + t; p < end; p += 256)
        atomicAdd(&deg[ebuf[p] & 511u], 1);
    __syncthreads();

    int d0 = deg[2 * t], d1 = deg[2 * t + 1];
    int s = d0 + d1;
    int incl = s;
    #pragma unroll
    for (int d = 1; d < 64; d <<= 1) {
        int u = __shfl_up(incl, d);
        if (lane >= d) incl += u;
    }
    if (lane == 63) wsum[w] = incl;
    __syncthreads();
    if (t < 4) {
        int v = wsum[t];
        int iv = v;
        #pragma unroll
        for (int d = 1; d < 4; d <<= 1) {
            int u = __shfl_up(iv, d, 4);
            if (t >= d) iv += u;
        }
        wsum[t] = iv - v;
    }
    __syncthreads();
    int ebase = wsum[w] + (incl - s);
    cur[2 * t] = ebase;
    cur[2 * t + 1] = ebase + d0;
    int n0 = node0 + 2 * t, n1 = n0 + 1;
    if (n0 < N_NODES) {
        off[n0] = base + ebase;
        dinv[n0] = 1.0f / (float)max(d0, 1);
    }
    if (n1 < N_NODES) {
        off[n1] = base + ebase + d0;
        dinv[n1] = 1.0f / (float)max(d1, 1);
    }
    if (j == 0 && t == 0) off[N_NODES] = N_EDGES;
    __syncthreads();

    for (int p = base + t; p < end; p += 256) {
        uint32_t ent = ebuf[p];
        int pos = atomicAdd(&cur[ent & 511u], 1);
        ssrc[base + pos] = (int)(ent >> 9);
    }
}

// ---------------- W pre-split into MFMA fragment order ----------------

__global__ void wfrag_kernel(const float* __restrict__ W1, const float* __restrict__ W2,
                             int C1, int NCT, int ntask,
                             short* __restrict__ fhi, short* __restrict__ flo) {
    int tau = blockIdx.x * 256 + threadIdx.x;
    if (tau >= ntask) return;
    int lane = tau & 63;
    int ct = (tau >> 6) % NCT;
    int ks = (tau >> 6) / NCT;
    int col = ct * 16 + (lane & 15);
    int k = ks * 32 + (lane >> 4) * 8;
    const float* p = (col < C1) ? &W1[(size_t)col * 128 + k]
                                : &W2[(size_t)(col - C1) * 128 + k];
    short8 h8, l8;
    #pragma unroll
    for (int j = 0; j < 8; ++j) {
        short h, l;
        bsplit(p[j], h, l);
        h8[j] = h; l8[j] = l;
    }
    *reinterpret_cast<short8*>(&fhi[(size_t)tau * 8]) = h8;
    *reinterpret_cast<short8*>(&flo[(size_t)tau * 8]) = l8;
}

// ---------------- MFMA GEMM, fp32 A (3-term split), bf16 outs via LDS — layer 0 ----------------

template<int C1, int C2>
__global__ __launch_bounds__(256)
void gemm_f32(const float* __restrict__ H, const short* __restrict__ Wfhi,
              const short* __restrict__ Wflo, const float* __restrict__ bias2,
              ushort* __restrict__ out1, ushort* __restrict__ out2) {
    constexpr int COUT = C1 + C2;       // 256
    constexpr int CT = COUT / 64;
    constexpr int NCT = COUT / 16;
    __shared__ short smem[16384];       // Ahi|Alo (32KB), re-aliased as C-tile
    short* Ahi = smem;
    short* Alo = smem + 8192;
    int t = threadIdx.x;
    int l = t & 63, w = t >> 6;
    int lr = l & 15, kg = l >> 4;
    int r0 = blockIdx.x * 64;
    int c_base = w * (COUT / 4);
    const bool is1 = (c_base < C1);

    #pragma unroll
    for (int it = 0; it < 4; ++it) {
        int lin = t + it * 256;
        int row = lin >> 4, ch = lin & 15;
        float av[8];
        if (r0 + row < N_NODES) {
            const float* p = &H[(size_t)(r0 + row) * 128 + ch * 8];
            float4 v0 = *reinterpret_cast<const float4*>(p);
            float4 v1 = *reinterpret_cast<const float4*>(p + 4);
            av[0] = v0.x; av[1] = v0.y; av[2] = v0.z; av[3] = v0.w;
            av[4] = v1.x; av[5] = v1.y; av[6] = v1.z; av[7] = v1.w;
        } else {
            #pragma unroll
            for (int j = 0; j < 8; ++j) av[j] = 0.f;
        }
        short8 h8, l8;
        #pragma unroll
        for (int j = 0; j < 8; ++j) {
            short h, lo2;
            bsplit(av[j], h, lo2);
            h8[j] = h; l8[j] = lo2;
        }
        int off = row * 128 + ((ch ^ (row & 7)) << 3);
        *reinterpret_cast<short8*>(&Ahi[off]) = h8;
        *reinterpret_cast<short8*>(&Alo[off]) = l8;
    }
    __syncthreads();

    f32x4 acc[4][CT];
    #pragma unroll
    for (int m = 0; m < 4; ++m)
        #pragma unroll
        for (int c = 0; c < CT; ++c)
            acc[m][c] = (f32x4){0.f, 0.f, 0.f, 0.f};

    #pragma unroll
    for (int ks = 0; ks < 4; ++ks) {
        int ch = ks * 4 + kg;
        short8 ahi[4], alo[4];
        #pragma unroll
        for (int m = 0; m < 4; ++m) {
            int row = m * 16 + lr;
            int off = row * 128 + ((ch ^ (row & 7)) << 3);
            ahi[m] = *reinterpret_cast<const short8*>(&Ahi[off]);
            alo[m] = *reinterpret_cast<const short8*>(&Alo[off]);
        }
        short8 bhi[CT], blo[CT];
        #pragma unroll
        for (int c = 0; c < CT; ++c) {
            int ctg = w * CT + c;
            size_t fo = ((size_t)(ks * NCT + ctg) * 64 + l) * 8;
            bhi[c] = *reinterpret_cast<const short8*>(&Wfhi[fo]);
            blo[c] = *reinterpret_cast<const short8*>(&Wflo[fo]);
        }
        #pragma unroll
        for (int m = 0; m < 4; ++m)
            #pragma unroll
            for (int c = 0; c < CT; ++c) {
                acc[m][c] = __builtin_amdgcn_mfma_f32_16x16x32_bf16(ahi[m], bhi[c], acc[m][c], 0, 0, 0);
                acc[m][c] = __builtin_amdgcn_mfma_f32_16x16x32_bf16(ahi[m], blo[c], acc[m][c], 0, 0, 0);
                acc[m][c] = __builtin_amdgcn_mfma_f32_16x16x32_bf16(alo[m], bhi[c], acc[m][c], 0, 0, 0);
            }
    }

    // epilogue: swizzled LDS C-tile -> coalesced uint4 stores
    float bb[CT];
    #pragma unroll
    for (int c = 0; c < CT; ++c) {
        int colg = c_base + c * 16 + lr;
        bb[c] = is1 ? 0.f : bias2[colg - C1];
    }
    __syncthreads();
    ushort* Ct = (ushort*)smem;         // [64][256], 32B-seg swizzle: seg ^ ((row>>2)&3)
    #pragma unroll
    for (int c = 0; c < CT; ++c) {
        int seg = c_base / 16 + c;
        #pragma unroll
        for (int m = 0; m < 4; ++m)
            #pragma unroll
            for (int r = 0; r < 4; ++r) {
                int row = m * 16 + kg * 4 + r;
                int sw = seg ^ ((row >> 2) & 3);
                Ct[row * 256 + sw * 16 + lr] = f2bf(acc[m][c][r] + bb[c]);
            }
    }
    __syncthreads();
    #pragma unroll
    for (int it = 0; it < 8; ++it) {
        int lin = it * 256 + t;
        int row = lin >> 5, chk = lin & 31;
        int grow = r0 + row;
        if (grow < N_NODES) {
            int sw = (chk >> 1) ^ ((row >> 2) & 3);
            uint4 v = *reinterpret_cast<const uint4*>(&Ct[row * 256 + sw * 16 + (chk & 1) * 8]);
            if (chk < 16)
                *reinterpret_cast<uint4*>(&out1[(size_t)grow * C1 + chk * 8]) = v;
            else
                *reinterpret_cast<uint4*>(&out2[(size_t)grow * C2 + (chk - 16) * 8]) = v;
        }
    }
}

// ---------------- MFMA GEMM, bf16 A (2-term) — layers 1,2 ----------------

template<int C1, int C2, bool ZF32>
__global__ __launch_bounds__(256)
void gemm_bf16(const ushort* __restrict__ H, const short* __restrict__ Wfhi,
               const short* __restrict__ Wflo, const float* __restrict__ bias2,
               ushort* __restrict__ out1, void* __restrict__ out2v) {
    constexpr int COUT = C1 + C2;
    constexpr int CT = COUT / 64;
    constexpr int NCT = COUT / 16;
    constexpr int SMEM = ZF32 ? 8192 : (64 * COUT > 8192 ? 64 * COUT : 8192);
    __shared__ short smem[SMEM];
    short* A = smem;
    int t = threadIdx.x;
    int l = t & 63, w = t >> 6;
    int lr = l & 15, kg = l >> 4;
    int r0 = blockIdx.x * 64;
    int c_base = w * (COUT / 4);
    const bool is1 = (c_base < C1);

    #pragma unroll
    for (int it = 0; it < 4; ++it) {
        int lin = t + it * 256;
        int row = lin >> 4, ch = lin & 15;
        short8 v = (short8){0, 0, 0, 0, 0, 0, 0, 0};
        if (r0 + row < N_NODES)
            v = *reinterpret_cast<const short8*>(&H[(size_t)(r0 + row) * 128 + ch * 8]);
        int off = row * 128 + ((ch ^ (row & 7)) << 3);
        *reinterpret_cast<short8*>(&A[off]) = v;
    }
    __syncthreads();

    f32x4 acc[4][CT];
    #pragma unroll
    for (int m = 0; m < 4; ++m)
        #pragma unroll
        for (int c = 0; c < CT; ++c)
            acc[m][c] = (f32x4){0.f, 0.f, 0.f, 0.f};

    #pragma unroll
    for (int ks = 0; ks < 4; ++ks) {
        int ch = ks * 4 + kg;
        short8 a[4];
        #pragma unroll
        for (int m = 0; m < 4; ++m) {
            int row = m * 16 + lr;
            int off = row * 128 + ((ch ^ (row & 7)) << 3);
            a[m] = *reinterpret_cast<const short8*>(&A[off]);
        }
        short8 bhi[CT], blo[CT];
        #pragma unroll
        for (int c = 0; c < CT; ++c) {
            int ctg = w * CT + c;
            size_t fo = ((size_t)(ks * NCT + ctg) * 64 + l) * 8;
            bhi[c] = *reinterpret_cast<const short8*>(&Wfhi[fo]);
            blo[c] = *reinterpret_cast<const short8*>(&Wflo[fo]);
        }
        #pragma unroll
        for (int m = 0; m < 4; ++m)
            #pragma unroll
            for (int c = 0; c < CT; ++c) {
                acc[m][c] = __builtin_amdgcn_mfma_f32_16x16x32_bf16(a[m], bhi[c], acc[m][c], 0, 0, 0);
                acc[m][c] = __builtin_amdgcn_mfma_f32_16x16x32_bf16(a[m], blo[c], acc[m][c], 0, 0, 0);
            }
    }

    if (!ZF32) {
        float bb[CT];
        #pragma unroll
        for (int c = 0; c < CT; ++c) {
            int colg = c_base + c * 16 + lr;
            bb[c] = is1 ? 0.f : bias2[colg - C1];
        }
        __syncthreads();
        ushort* Ct = (ushort*)smem;
        #pragma unroll
        for (int c = 0; c < CT; ++c) {
            int seg = c_base / 16 + c;
            #pragma unroll
            for (int m = 0; m < 4; ++m)
                #pragma unroll
                for (int r = 0; r < 4; ++r) {
                    int row = m * 16 + kg * 4 + r;
                    int sw = seg ^ ((row >> 2) & 3);
                    Ct[row * COUT + sw * 16 + lr] = f2bf(acc[m][c][r] + bb[c]);
                }
        }
        __syncthreads();
        constexpr int CHR = COUT / 8;
        #pragma unroll
        for (int it = 0; it < 64 * CHR / 256; ++it) {
            int lin = it * 256 + t;
            int row = lin / CHR, chk = lin % CHR;
            int grow = r0 + row;
            if (grow < N_NODES) {
                int sw = (chk >> 1) ^ ((row >> 2) & 3);
                uint4 v = *reinterpret_cast<const uint4*>(&Ct[row * COUT + sw * 16 + (chk & 1) * 8]);
                if (chk < C1 / 8)
                    *reinterpret_cast<uint4*>(&out1[(size_t)grow * C1 + chk * 8]) = v;
                else
                    *reinterpret_cast<uint4*>(&((ushort*)out2v)[(size_t)grow * C2 + (chk - C1 / 8) * 8]) = v;
            }
        }
    } else {
        __syncthreads();
        ushort* Yt = (ushort*)smem;     // [64][C1]
        if (is1) {
            #pragma unroll
            for (int c = 0; c < CT; ++c) {
                int seg = c_base / 16 + c;
                #pragma unroll
                for (int m = 0; m < 4; ++m)
                    #pragma unroll
                    for (int r = 0; r < 4; ++r) {
                        int row = m * 16 + kg * 4 + r;
                        int sw = seg ^ ((row >> 2) & 3);
                        Yt[row * C1 + sw * 16 + lr] = f2bf(acc[m][c][r]);
                    }
            }
        } else {
            float* out2 = (float*)out2v;
            #pragma unroll
            for (int c = 0; c < CT; ++c) {
                int col = c_base - C1 + c * 16 + lr;
                float bbv = bias2[col];
                #pragma unroll
                for (int m = 0; m < 4; ++m)
                    #pragma unroll
                    for (int r = 0; r < 4; ++r) {
                        int row = r0 + m * 16 + kg * 4 + r;
                        if (row < N_NODES)
                            out2[(size_t)row * C2 + col] = acc[m][c][r] + bbv;
                    }
            }
        }
        __syncthreads();
        constexpr int CHR = C1 / 8;
        #pragma unroll
        for (int it = 0; it < 64 * CHR / 256; ++it) {
            int lin = it * 256 + t;
            int row = lin / CHR, chk = lin % CHR;
            int grow = r0 + row;
            if (grow < N_NODES) {
                int sw = (chk >> 1) ^ ((row >> 2) & 3);
                uint4 v = *reinterpret_cast<const uint4*>(&Yt[row * C1 + sw * 16 + (chk & 1) * 8]);
                *reinterpret_cast<uint4*>(&out1[(size_t)grow * C1 + chk * 8]) = v;
            }
        }
    }
}

// ---------------- wave-per-node aggregation, 64-ch passes, sw-pipelined ----------------
// Grid = nhalves*NBK blocks; half = bid/NBK selects channel window [half*64, half*64+64).
// FINAL=false: Z bf16, out bf16 + relu.  FINAL=true: Z fp32, out fp32, no relu.

template<bool FINAL>
__global__ __launch_bounds__(256)
void agg8(const ushort* __restrict__ Y, const void* __restrict__ Zv,
          const int* __restrict__ off, const int* __restrict__ ssrc,
          const float* __restrict__ dinv, void* __restrict__ outv, int RSE) {
    int t = threadIdx.x, l = t & 63;
    int bid = blockIdx.x;
    int nb = bid % NBK;
    int half = bid / NBK;
    int i = nb * 4 + (t >> 6);
    int chunk = l & 7;          // 8 chunks x 8 elements = 64 channels per pass
    int eslot = l >> 3;         // 8 parallel edge slots
    int cbase = half * 64 + chunk * 8;
    const ushort* Yb = Y + cbase;

    int p0 = off[i], p1 = off[i + 1];
    float acc[8] = {0.f, 0.f, 0.f, 0.f, 0.f, 0.f, 0.f, 0.f};

    #define LDQ(q, v, a)  { a = (q) < p1; if (a) { int s_ = ssrc[q]; \
        v = *reinterpret_cast<const uint4*>(&Yb[(size_t)s_ * RSE]); } }
    #define ACCU(v) { acc_word(v.x, acc[0], acc[1]); acc_word(v.y, acc[2], acc[3]); \
                      acc_word(v.z, acc[4], acc[5]); acc_word(v.w, acc[6], acc[7]); }

    uint4 c0, c1;
    bool a0, a1;
    LDQ(p0 + eslot, c0, a0)
    LDQ(p0 + 8 + eslot, c1, a1)
    for (int p = p0 + 16; p < p1; p += 16) {
        uint4 n0, n1;
        bool b0, b1;
        LDQ(p + eslot, n0, b0)
        LDQ(p + 8 + eslot, n1, b1)
        if (a0) ACCU(c0)
        if (a1) ACCU(c1)
        c0 = n0; c1 = n1; a0 = b0; a1 = b1;
    }
    if (a0) ACCU(c0)
    if (a1) ACCU(c1)
    #undef LDQ
    #undef ACCU

    #pragma unroll
    for (int d = 8; d < 64; d <<= 1)
        #pragma unroll
        for (int j = 0; j < 8; ++j)
            acc[j] += __shfl_xor(acc[j], d);

    if (eslot == 0) {
        float di = dinv[i];
        size_t eo = (size_t)i * RSE + cbase;
        float zz[8];
        if (FINAL) {
            const float* zp = (const float*)Zv + eo;
            float4 z0 = *reinterpret_cast<const float4*>(zp);
            float4 z1 = *reinterpret_cast<const float4*>(zp + 4);
            zz[0] = z0.x; zz[1] = z0.y; zz[2] = z0.z; zz[3] = z0.w;
            zz[4] = z1.x; zz[5] = z1.y; zz[6] = z1.z; zz[7] = z1.w;
        } else {
            uint4 zv = *reinterpret_cast<const uint4*>((const ushort*)Zv + eo);
            uint32_t wd[4] = {zv.x, zv.y, zv.z, zv.w};
            #pragma unroll
            for (int j = 0; j < 4; ++j) {
                zz[2 * j]     = bfloat(wd[j] << 16);
                zz[2 * j + 1] = bfloat(wd[j] & 0xFFFF0000u);
            }
        }
        float r[8];
        #pragma unroll
        for (int j = 0; j < 8; ++j) {
            r[j] = acc[j] * di + zz[j];
            if (!FINAL) r[j] = fmaxf(r[j], 0.f);
        }
        if (FINAL) {
            float* op = (float*)outv + eo;
            *reinterpret_cast<float4*>(op)     = make_float4(r[0], r[1], r[2], r[3]);
            *reinterpret_cast<float4*>(op + 4) = make_float4(r[4], r[5], r[6], r[7]);
        } else {
            uint4 o;
            o.x = (uint32_t)f2bf(r[0]) | ((uint32_t)f2bf(r[1]) << 16);
            o.y = (uint32_t)f2bf(r[2]) | ((uint32_t)f2bf(r[3]) << 16);
            o.z = (uint32_t)f2bf(r[4]) | ((uint32_t)f2bf(r[5]) << 16);
            o.w = (uint32_t)f2bf(r[6]) | ((uint32_t)f2bf(r[7]) << 16);
            *reinterpret_cast<uint4*>((ushort*)outv + eo) = o;
        }
    }
}

// ---------------- launch ----------------

extern "C" void kernel_launch(void* const* d_in, const int* in_sizes, int n_in,
                              void* d_out, int out_size, void* d_ws, size_t ws_size,
                              hipStream_t stream) {
    const float* x   = (const float*)d_in[0];
    const int*   ei  = (const int*)d_in[2];
    const float* Wl0 = (const float*)d_in[3];
    const float* bl0 = (const float*)d_in[4];
    const float* Wr0 = (const float*)d_in[5];
    const float* Wl1 = (const float*)d_in[6];
    const float* bl1 = (const float*)d_in[7];
    const float* Wr1 = (const float*)d_in[8];
    const float* Wl2 = (const float*)d_in[9];
    const float* bl2 = (const float*)d_in[10];
    const float* Wr2 = (const float*)d_in[11];
    float* out = (float*)d_out;

    char* ws = (char*)d_ws;
    int*      H    = (int*)(ws + 0);                        // 306,544 B
    int*      boff = (int*)(ws + (size_t)(384 << 10));      // 788 B
    int*      off  = (int*)(ws + (size_t)(512 << 10));      // 400,004 B
    float*    dinv = (float*)(ws + (size_t)(960 << 10));    // 400,000 B
    uint32_t* ebuf = (uint32_t*)(ws + (size_t)(1400 << 10));// 6.4 MB
    int*      ssrc = (int*)(ws + (size_t)(1400 << 10) + (size_t)(7 << 20)); // 6.4 MB
    short* w0hi = (short*)(ws + (size_t)(16 << 20));
    short* w0lo = w0hi + 32768;
    short* w1hi = w0lo + 32768;
    short* w1lo = w1hi + 32768;
    short* w2hi = w1lo + 32768;
    short* w2lo = w2hi + 16384;                             // ends ~16.3 MB
    ushort* Ybf = (ushort*)(ws + (size_t)(18 << 20));       // 25.6 MB -> ends 43.6
    ushort* Zbf = (ushort*)(ws + (size_t)(44 << 20));       // 25.6 MB -> ends 69.6 (also fp32 z2)
    ushort* Hbf = (ushort*)(ws + (size_t)(70 << 20));       // 25.6 MB -> ends 95.6

    const int* srcp = ei;
    const int* dstp = ei + N_EDGES;

    hist_kernel<<<HB, 256, 0, stream>>>(dstp, H);
    scanbase_kernel<<<1, 256, 0, stream>>>(H, boff);
    scatter_kernel<<<HB, 256, 0, stream>>>(srcp, dstp, H, ebuf);
    bucket_csr<<<NCB, 256, 0, stream>>>(ebuf, boff, off, dinv, ssrc);

    wfrag_kernel<<<16, 256, 0, stream>>>(Wl0, Wr0, 128, 16, 4096, w0hi, w0lo);
    wfrag_kernel<<<16, 256, 0, stream>>>(Wl1, Wr1, 128, 16, 4096, w1hi, w1lo);
    wfrag_kernel<<<8, 256, 0, stream>>>(Wl2, Wr2, 64, 8, 2048, w2hi, w2lo);

    int ggrid = (N_NODES + 63) / 64;   // 1563

    // layer 0: fp32 x -> 3-term split GEMM -> bf16 y,z
    gemm_f32<128, 128><<<ggrid, 256, 0, stream>>>(x, w0hi, w0lo, bl0, Ybf, Zbf);
    agg8<false><<<2 * NBK, 256, 0, stream>>>(Ybf, Zbf, off, ssrc, dinv, Hbf, 128);

    // layer 1: bf16 h -> 2-term GEMM -> bf16 y,z
    gemm_bf16<128, 128, false><<<ggrid, 256, 0, stream>>>(Hbf, w1hi, w1lo, bl1, Ybf, Zbf);
    agg8<false><<<2 * NBK, 256, 0, stream>>>(Ybf, Zbf, off, ssrc, dinv, Hbf, 128);

    // layer 2: bf16 h -> 2-term GEMM -> bf16 y2, fp32 z2; final agg to fp32 out
    gemm_bf16<64, 64, true><<<ggrid, 256, 0, stream>>>(Hbf, w2hi, w2lo, bl2, Ybf, (void*)Zbf);
    agg8<true><<<NBK, 256, 0, stream>>>(Ybf, (const void*)Zbf, off, ssrc, dinv, out, 64);
}

// Round 12
// 329.844 us; speedup vs baseline: 1.1002x; 1.1002x over previous
//
#include <hip/hip_runtime.h>
#include <cstdint>

#define N_NODES 100000
#define N_EDGES 1600000

constexpr int NCB = 196;   // coarse buckets: dst >> 9 (512 nodes each)
constexpr int HB  = 391;   // binning blocks, 4096 edges each
constexpr int NBK = N_NODES / 4; // 25000 agg blocks (4 nodes/block)

typedef __attribute__((ext_vector_type(8))) short short8;
typedef __attribute__((ext_vector_type(4))) float f32x4;

__device__ inline uint32_t fbits(float f) { union { float f; uint32_t u; } c; c.f = f; return c.u; }
__device__ inline float bfloat(uint32_t u) { union { uint32_t u; float f; } c; c.u = u; return c.f; }

__device__ inline void bsplit(float a, short& hi, short& lo) {
    uint32_t h = fbits(a) & 0xFFFF0000u;
    float fl = a - bfloat(h);
    hi = (short)(h >> 16);
    lo = (short)(fbits(fl) >> 16);
}

__device__ inline ushort f2bf(float f) { // RNE fp32->bf16
    uint32_t u = fbits(f);
    return (ushort)((u + 0x7FFFu + ((u >> 16) & 1u)) >> 16);
}

// bf16-pair accumulate (proven unpack path)
__device__ inline void acc_word(uint32_t w, float& lo, float& hi) {
    lo += bfloat(w << 16);
    hi += bfloat(w & 0xFFFF0000u);
}

// ---------------- binning: hist -> scan/bases -> scatter ----------------

__global__ __launch_bounds__(256)
void hist_kernel(const int* __restrict__ dst, int* __restrict__ H) {
    __shared__ int h[NCB];
    for (int i = threadIdx.x; i < NCB; i += 256) h[i] = 0;
    __syncthreads();
    int e0 = blockIdx.x * 4096;
    #pragma unroll
    for (int it = 0; it < 16; ++it) {
        int e = e0 + it * 256 + threadIdx.x;
        if (e < N_EDGES) atomicAdd(&h[dst[e] >> 9], 1);
    }
    __syncthreads();
    for (int i = threadIdx.x; i < NCB; i += 256) H[blockIdx.x * NCB + i] = h[i];
}

__global__ __launch_bounds__(256)
void scanbase_kernel(int* __restrict__ H, int* __restrict__ boff) {
    __shared__ int tot[NCB];
    __shared__ int base[NCB + 1];
    int j = threadIdx.x;
    if (j < NCB) {
        int s = 0;
        for (int b = 0; b < HB; ++b) s += H[b * NCB + j];
        tot[j] = s;
    }
    __syncthreads();
    if (j == 0) {
        int run = 0;
        for (int k = 0; k < NCB; ++k) { base[k] = run; run += tot[k]; }
        base[NCB] = run;
    }
    __syncthreads();
    if (j <= NCB) boff[j] = base[j];
    if (j < NCB) {
        int run = base[j];
        for (int b = 0; b < HB; ++b) {
            int v = H[b * NCB + j];
            H[b * NCB + j] = run;
            run += v;
        }
    }
}

__global__ __launch_bounds__(256)
void scatter_kernel(const int* __restrict__ src, const int* __restrict__ dst,
                    const int* __restrict__ H, uint32_t* __restrict__ ebuf) {
    __shared__ int cur[NCB];
    for (int i = threadIdx.x; i < NCB; i += 256) cur[i] = H[blockIdx.x * NCB + i];
    __syncthreads();
    int e0 = blockIdx.x * 4096;
    #pragma unroll
    for (int it = 0; it < 16; ++it) {
        int e = e0 + it * 256 + threadIdx.x;
        if (e < N_EDGES) {
            int d = dst[e];
            int p = atomicAdd(&cur[d >> 9], 1);
            ebuf[p] = ((uint32_t)src[e] << 9) | (uint32_t)(d & 511);
        }
    }
}

// ---------------- bucket -> exact CSR ----------------

__global__ __launch_bounds__(256)
void bucket_csr(const uint32_t* __restrict__ ebuf, const int* __restrict__ boff,
                int* __restrict__ off, float* __restrict__ dinv,
                int* __restrict__ ssrc) {
    __shared__ int deg[512];
    __shared__ int cur[512];
    __shared__ int wsum[4];
    int t = threadIdx.x, lane = t & 63, w = t >> 6;
    int j = blockIdx.x;
    int base = boff[j], end = boff[j + 1];
    int node0 = j << 9;

    deg[t] = 0; deg[t + 256] = 0;
    __syncthreads();

    for (int p = base + t; p < end; p += 256)
        atomicAdd(&deg[ebuf[p] & 511u], 1);
    __syncthreads();

    int d0 = deg[2 * t], d1 = deg[2 * t + 1];
    int s = d0 + d1;
    int incl = s;
    #pragma unroll
    for (int d = 1; d < 64; d <<= 1) {
        int u = __shfl_up(incl, d);
        if (lane >= d) incl += u;
    }
    if (lane == 63) wsum[w] = incl;
    __syncthreads();
    if (t < 4) {
        int v = wsum[t];
        int iv = v;
        #pragma unroll
        for (int d = 1; d < 4; d <<= 1) {
            int u = __shfl_up(iv, d, 4);
            if (t >= d) iv += u;
        }
        wsum[t] = iv - v;
    }
    __syncthreads();
    int ebase = wsum[w] + (incl - s);
    cur[2 * t] = ebase;
    cur[2 * t + 1] = ebase + d0;
    int n0 = node0 + 2 * t, n1 = n0 + 1;
    if (n0 < N_NODES) {
        off[n0] = base + ebase;
        dinv[n0] = 1.0f / (float)max(d0, 1);
    }
    if (n1 < N_NODES) {
        off[n1] = base + ebase + d0;
        dinv[n1] = 1.0f / (float)max(d1, 1);
    }
    if (j == 0 && t == 0) off[N_NODES] = N_EDGES;
    __syncthreads();

    for (int p = base + t; p < end; p += 256) {
        uint32_t ent = ebuf[p];
        int pos = atomicAdd(&cur[ent & 511u], 1);
        ssrc[base + pos] = (int)(ent >> 9);
    }
}

// ---------------- W pre-split into MFMA fragment order ----------------

__global__ void wfrag_kernel(const float* __restrict__ W1, const float* __restrict__ W2,
                             int C1, int NCT, int ntask,
                             short* __restrict__ fhi, short* __restrict__ flo) {
    int tau = blockIdx.x * 256 + threadIdx.x;
    if (tau >= ntask) return;
    int lane = tau & 63;
    int ct = (tau >> 6) % NCT;
    int ks = (tau >> 6) / NCT;
    int col = ct * 16 + (lane & 15);
    int k = ks * 32 + (lane >> 4) * 8;
    const float* p = (col < C1) ? &W1[(size_t)col * 128 + k]
                                : &W2[(size_t)(col - C1) * 128 + k];
    short8 h8, l8;
    #pragma unroll
    for (int j = 0; j < 8; ++j) {
        short h, l;
        bsplit(p[j], h, l);
        h8[j] = h; l8[j] = l;
    }
    *reinterpret_cast<short8*>(&fhi[(size_t)tau * 8]) = h8;
    *reinterpret_cast<short8*>(&flo[(size_t)tau * 8]) = l8;
}

// ---------------- MFMA GEMM, fp32 A (3-term split), bf16 outs via LDS — layer 0 ----------------

template<int C1, int C2>
__global__ __launch_bounds__(256)
void gemm_f32(const float* __restrict__ H, const short* __restrict__ Wfhi,
              const short* __restrict__ Wflo, const float* __restrict__ bias2,
              ushort* __restrict__ out1, ushort* __restrict__ out2) {
    constexpr int COUT = C1 + C2;       // 256
    constexpr int CT = COUT / 64;
    constexpr int NCT = COUT / 16;
    __shared__ short smem[16384];       // Ahi|Alo (32KB), re-aliased as C-tile
    short* Ahi = smem;
    short* Alo = smem + 8192;
    int t = threadIdx.x;
    int l = t & 63, w = t >> 6;
    int lr = l & 15, kg = l >> 4;
    int r0 = blockIdx.x * 64;
    int c_base = w * (COUT / 4);
    const bool is1 = (c_base < C1);

    #pragma unroll
    for (int it = 0; it < 4; ++it) {
        int lin = t + it * 256;
        int row = lin >> 4, ch = lin & 15;
        float av[8];
        if (r0 + row < N_NODES) {
            const float* p = &H[(size_t)(r0 + row) * 128 + ch * 8];
            float4 v0 = *reinterpret_cast<const float4*>(p);
            float4 v1 = *reinterpret_cast<const float4*>(p + 4);
            av[0] = v0.x; av[1] = v0.y; av[2] = v0.z; av[3] = v0.w;
            av[4] = v1.x; av[5] = v1.y; av[6] = v1.z; av[7] = v1.w;
        } else {
            #pragma unroll
            for (int j = 0; j < 8; ++j) av[j] = 0.f;
        }
        short8 h8, l8;
        #pragma unroll
        for (int j = 0; j < 8; ++j) {
            short h, lo2;
            bsplit(av[j], h, lo2);
            h8[j] = h; l8[j] = lo2;
        }
        int off = row * 128 + ((ch ^ (row & 7)) << 3);
        *reinterpret_cast<short8*>(&Ahi[off]) = h8;
        *reinterpret_cast<short8*>(&Alo[off]) = l8;
    }
    __syncthreads();

    f32x4 acc[4][CT];
    #pragma unroll
    for (int m = 0; m < 4; ++m)
        #pragma unroll
        for (int c = 0; c < CT; ++c)
            acc[m][c] = (f32x4){0.f, 0.f, 0.f, 0.f};

    #pragma unroll
    for (int ks = 0; ks < 4; ++ks) {
        int ch = ks * 4 + kg;
        short8 ahi[4], alo[4];
        #pragma unroll
        for (int m = 0; m < 4; ++m) {
            int row = m * 16 + lr;
            int off = row * 128 + ((ch ^ (row & 7)) << 3);
            ahi[m] = *reinterpret_cast<const short8*>(&Ahi[off]);
            alo[m] = *reinterpret_cast<const short8*>(&Alo[off]);
        }
        short8 bhi[CT], blo[CT];
        #pragma unroll
        for (int c = 0; c < CT; ++c) {
            int ctg = w * CT + c;
            size_t fo = ((size_t)(ks * NCT + ctg) * 64 + l) * 8;
            bhi[c] = *reinterpret_cast<const short8*>(&Wfhi[fo]);
            blo[c] = *reinterpret_cast<const short8*>(&Wflo[fo]);
        }
        #pragma unroll
        for (int m = 0; m < 4; ++m)
            #pragma unroll
            for (int c = 0; c < CT; ++c) {
                acc[m][c] = __builtin_amdgcn_mfma_f32_16x16x32_bf16(ahi[m], bhi[c], acc[m][c], 0, 0, 0);
                acc[m][c] = __builtin_amdgcn_mfma_f32_16x16x32_bf16(ahi[m], blo[c], acc[m][c], 0, 0, 0);
                acc[m][c] = __builtin_amdgcn_mfma_f32_16x16x32_bf16(alo[m], bhi[c], acc[m][c], 0, 0, 0);
            }
    }

    // epilogue: swizzled LDS C-tile -> coalesced uint4 stores
    float bb[CT];
    #pragma unroll
    for (int c = 0; c < CT; ++c) {
        int colg = c_base + c * 16 + lr;
        bb[c] = is1 ? 0.f : bias2[colg - C1];
    }
    __syncthreads();
    ushort* Ct = (ushort*)smem;         // [64][256], 32B-seg swizzle: seg ^ ((row>>2)&3)
    #pragma unroll
    for (int c = 0; c < CT; ++c) {
        int seg = c_base / 16 + c;
        #pragma unroll
        for (int m = 0; m < 4; ++m)
            #pragma unroll
            for (int r = 0; r < 4; ++r) {
                int row = m * 16 + kg * 4 + r;
                int sw = seg ^ ((row >> 2) & 3);
                Ct[row * 256 + sw * 16 + lr] = f2bf(acc[m][c][r] + bb[c]);
            }
    }
    __syncthreads();
    #pragma unroll
    for (int it = 0; it < 8; ++it) {
        int lin = it * 256 + t;
        int row = lin >> 5, chk = lin & 31;
        int grow = r0 + row;
        if (grow < N_NODES) {
            int sw = (chk >> 1) ^ ((row >> 2) & 3);
            uint4 v = *reinterpret_cast<const uint4*>(&Ct[row * 256 + sw * 16 + (chk & 1) * 8]);
            if (chk < 16)
                *reinterpret_cast<uint4*>(&out1[(size_t)grow * C1 + chk * 8]) = v;
            else
                *reinterpret_cast<uint4*>(&out2[(size_t)grow * C2 + (chk - 16) * 8]) = v;
        }
    }
}

// ---------------- MFMA GEMM, bf16 A (2-term) — layers 1,2 ----------------

template<int C1, int C2, bool ZF32>
__global__ __launch_bounds__(256)
void gemm_bf16(const ushort* __restrict__ H, const short* __restrict__ Wfhi,
               const short* __restrict__ Wflo, const float* __restrict__ bias2,
               ushort* __restrict__ out1, void* __restrict__ out2v) {
    constexpr int COUT = C1 + C2;
    constexpr int CT = COUT / 64;
    constexpr int NCT = COUT / 16;
    constexpr int SMEM = ZF32 ? 8192 : (64 * COUT > 8192 ? 64 * COUT : 8192);
    __shared__ short smem[SMEM];
    short* A = smem;
    int t = threadIdx.x;
    int l = t & 63, w = t >> 6;
    int lr = l & 15, kg = l >> 4;
    int r0 = blockIdx.x * 64;
    int c_base = w * (COUT / 4);
    const bool is1 = (c_base < C1);

    #pragma unroll
    for (int it = 0; it < 4; ++it) {
        int lin = t + it * 256;
        int row = lin >> 4, ch = lin & 15;
        short8 v = (short8){0, 0, 0, 0, 0, 0, 0, 0};
        if (r0 + row < N_NODES)
            v = *reinterpret_cast<const short8*>(&H[(size_t)(r0 + row) * 128 + ch * 8]);
        int off = row * 128 + ((ch ^ (row & 7)) << 3);
        *reinterpret_cast<short8*>(&A[off]) = v;
    }
    __syncthreads();

    f32x4 acc[4][CT];
    #pragma unroll
    for (int m = 0; m < 4; ++m)
        #pragma unroll
        for (int c = 0; c < CT; ++c)
            acc[m][c] = (f32x4){0.f, 0.f, 0.f, 0.f};

    #pragma unroll
    for (int ks = 0; ks < 4; ++ks) {
        int ch = ks * 4 + kg;
        short8 a[4];
        #pragma unroll
        for (int m = 0; m < 4; ++m) {
            int row = m * 16 + lr;
            int off = row * 128 + ((ch ^ (row & 7)) << 3);
            a[m] = *reinterpret_cast<const short8*>(&A[off]);
        }
        short8 bhi[CT], blo[CT];
        #pragma unroll
        for (int c = 0; c < CT; ++c) {
            int ctg = w * CT + c;
            size_t fo = ((size_t)(ks * NCT + ctg) * 64 + l) * 8;
            bhi[c] = *reinterpret_cast<const short8*>(&Wfhi[fo]);
            blo[c] = *reinterpret_cast<const short8*>(&Wflo[fo]);
        }
        #pragma unroll
        for (int m = 0; m < 4; ++m)
            #pragma unroll
            for (int c = 0; c < CT; ++c) {
                acc[m][c] = __builtin_amdgcn_mfma_f32_16x16x32_bf16(a[m], bhi[c], acc[m][c], 0, 0, 0);
                acc[m][c] = __builtin_amdgcn_mfma_f32_16x16x32_bf16(a[m], blo[c], acc[m][c], 0, 0, 0);
            }
    }

    if (!ZF32) {
        float bb[CT];
        #pragma unroll
        for (int c = 0; c < CT; ++c) {
            int colg = c_base + c * 16 + lr;
            bb[c] = is1 ? 0.f : bias2[colg - C1];
        }
        __syncthreads();
        ushort* Ct = (ushort*)smem;
        #pragma unroll
        for (int c = 0; c < CT; ++c) {
            int seg = c_base / 16 + c;
            #pragma unroll
            for (int m = 0; m < 4; ++m)
                #pragma unroll
                for (int r = 0; r < 4; ++r) {
                    int row = m * 16 + kg * 4 + r;
                    int sw = seg ^ ((row >> 2) & 3);
                    Ct[row * COUT + sw * 16 + lr] = f2bf(acc[m][c][r] + bb[c]);
                }
        }
        __syncthreads();
        constexpr int CHR = COUT / 8;
        #pragma unroll
        for (int it = 0; it < 64 * CHR / 256; ++it) {
            int lin = it * 256 + t;
            int row = lin / CHR, chk = lin % CHR;
            int grow = r0 + row;
            if (grow < N_NODES) {
                int sw = (chk >> 1) ^ ((row >> 2) & 3);
                uint4 v = *reinterpret_cast<const uint4*>(&Ct[row * COUT + sw * 16 + (chk & 1) * 8]);
                if (chk < C1 / 8)
                    *reinterpret_cast<uint4*>(&out1[(size_t)grow * C1 + chk * 8]) = v;
                else
                    *reinterpret_cast<uint4*>(&((ushort*)out2v)[(size_t)grow * C2 + (chk - C1 / 8) * 8]) = v;
            }
        }
    } else {
        __syncthreads();
        ushort* Yt = (ushort*)smem;     // [64][C1]
        if (is1) {
            #pragma unroll
            for (int c = 0; c < CT; ++c) {
                int seg = c_base / 16 + c;
                #pragma unroll
                for (int m = 0; m < 4; ++m)
                    #pragma unroll
                    for (int r = 0; r < 4; ++r) {
                        int row = m * 16 + kg * 4 + r;
                        int sw = seg ^ ((row >> 2) & 3);
                        Yt[row * C1 + sw * 16 + lr] = f2bf(acc[m][c][r]);
                    }
            }
        } else {
            float* out2 = (float*)out2v;
            #pragma unroll
            for (int c = 0; c < CT; ++c) {
                int col = c_base - C1 + c * 16 + lr;
                float bbv = bias2[col];
                #pragma unroll
                for (int m = 0; m < 4; ++m)
                    #pragma unroll
                    for (int r = 0; r < 4; ++r) {
                        int row = r0 + m * 16 + kg * 4 + r;
                        if (row < N_NODES)
                            out2[(size_t)row * C2 + col] = acc[m][c][r] + bbv;
                    }
            }
        }
        __syncthreads();
        constexpr int CHR = C1 / 8;
        #pragma unroll
        for (int it = 0; it < 64 * CHR / 256; ++it) {
            int lin = it * 256 + t;
            int row = lin / CHR, chk = lin % CHR;
            int grow = r0 + row;
            if (grow < N_NODES) {
                int sw = (chk >> 1) ^ ((row >> 2) & 3);
                uint4 v = *reinterpret_cast<const uint4*>(&Yt[row * C1 + sw * 16 + (chk & 1) * 8]);
                *reinterpret_cast<uint4*>(&out1[(size_t)grow * C1 + chk * 8]) = v;
            }
        }
    }
}

// ---------------- wave-per-node aggregation, full-row, depth-2 pipelined ----------------
// One wave per node; lanes = (chunk = l % NCH, eslot = l / NCH).
// FINAL=false: Z bf16, out bf16 + relu.  FINAL=true: Z fp32, out fp32, no relu.

template<int C, bool FINAL>
__global__ __launch_bounds__(256)
void agg_wave(const ushort* __restrict__ Y, const void* __restrict__ Zv,
              const int* __restrict__ off, const int* __restrict__ ssrc,
              const float* __restrict__ dinv, void* __restrict__ outv) {
    constexpr int NCH = C / 8;       // 16B chunks per row: 16 (C=128) / 8 (C=64)
    constexpr int ESL = 64 / NCH;    // parallel edge slots: 4 / 8
    int t = threadIdx.x, l = t & 63;
    int i = blockIdx.x * 4 + (t >> 6);
    int chunk = l & (NCH - 1);
    int eslot = l / NCH;
    const ushort* Yb = Y + chunk * 8;

    int p0 = off[i], p1 = off[i + 1];
    float acc[8] = {0.f, 0.f, 0.f, 0.f, 0.f, 0.f, 0.f, 0.f};

    #define LDQ(q, v, a)  { a = (q) < p1; if (a) { int s_ = ssrc[q]; \
        v = *reinterpret_cast<const uint4*>(&Yb[(size_t)s_ * C]); } }
    #define ACCU(v) { acc_word(v.x, acc[0], acc[1]); acc_word(v.y, acc[2], acc[3]); \
                      acc_word(v.z, acc[4], acc[5]); acc_word(v.w, acc[6], acc[7]); }

    uint4 c0, c1;
    bool a0, a1;
    LDQ(p0 + eslot, c0, a0)
    LDQ(p0 + ESL + eslot, c1, a1)
    for (int p = p0 + 2 * ESL; p < p1; p += 2 * ESL) {
        uint4 n0, n1;
        bool b0, b1;
        LDQ(p + eslot, n0, b0)
        LDQ(p + ESL + eslot, n1, b1)
        if (a0) ACCU(c0)
        if (a1) ACCU(c1)
        c0 = n0; c1 = n1; a0 = b0; a1 = b1;
    }
    if (a0) ACCU(c0)
    if (a1) ACCU(c1)
    #undef LDQ
    #undef ACCU

    #pragma unroll
    for (int d = NCH; d < 64; d <<= 1)
        #pragma unroll
        for (int j = 0; j < 8; ++j)
            acc[j] += __shfl_xor(acc[j], d);

    if (eslot == 0) {
        float di = dinv[i];
        size_t eo = (size_t)i * C + chunk * 8;
        float zz[8];
        if (FINAL) {
            const float* zp = (const float*)Zv + eo;
            float4 z0 = *reinterpret_cast<const float4*>(zp);
            float4 z1 = *reinterpret_cast<const float4*>(zp + 4);
            zz[0] = z0.x; zz[1] = z0.y; zz[2] = z0.z; zz[3] = z0.w;
            zz[4] = z1.x; zz[5] = z1.y; zz[6] = z1.z; zz[7] = z1.w;
        } else {
            uint4 zv = *reinterpret_cast<const uint4*>((const ushort*)Zv + eo);
            uint32_t wd[4] = {zv.x, zv.y, zv.z, zv.w};
            #pragma unroll
            for (int j = 0; j < 4; ++j) {
                zz[2 * j]     = bfloat(wd[j] << 16);
                zz[2 * j + 1] = bfloat(wd[j] & 0xFFFF0000u);
            }
        }
        float r[8];
        #pragma unroll
        for (int j = 0; j < 8; ++j) {
            r[j] = acc[j] * di + zz[j];
            if (!FINAL) r[j] = fmaxf(r[j], 0.f);
        }
        if (FINAL) {
            float* op = (float*)outv + eo;
            *reinterpret_cast<float4*>(op)     = make_float4(r[0], r[1], r[2], r[3]);
            *reinterpret_cast<float4*>(op + 4) = make_float4(r[4], r[5], r[6], r[7]);
        } else {
            uint4 o;
            o.x = (uint32_t)f2bf(r[0]) | ((uint32_t)f2bf(r[1]) << 16);
            o.y = (uint32_t)f2bf(r[2]) | ((uint32_t)f2bf(r[3]) << 16);
            o.z = (uint32_t)f2bf(r[4]) | ((uint32_t)f2bf(r[5]) << 16);
            o.w = (uint32_t)f2bf(r[6]) | ((uint32_t)f2bf(r[7]) << 16);
            *reinterpret_cast<uint4*>((ushort*)outv + eo) = o;
        }
    }
}

// ---------------- launch ----------------

extern "C" void kernel_launch(void* const* d_in, const int* in_sizes, int n_in,
                              void* d_out, int out_size, void* d_ws, size_t ws_size,
                              hipStream_t stream) {
    const float* x   = (const float*)d_in[0];
    const int*   ei  = (const int*)d_in[2];
    const float* Wl0 = (const float*)d_in[3];
    const float* bl0 = (const float*)d_in[4];
    const float* Wr0 = (const float*)d_in[5];
    const float* Wl1 = (const float*)d_in[6];
    const float* bl1 = (const float*)d_in[7];
    const float* Wr1 = (const float*)d_in[8];
    const float* Wl2 = (const float*)d_in[9];
    const float* bl2 = (const float*)d_in[10];
    const float* Wr2 = (const float*)d_in[11];
    float* out = (float*)d_out;

    char* ws = (char*)d_ws;
    int*      H    = (int*)(ws + 0);                        // 306,544 B
    int*      boff = (int*)(ws + (size_t)(384 << 10));      // 788 B
    int*      off  = (int*)(ws + (size_t)(512 << 10));      // 400,004 B
    float*    dinv = (float*)(ws + (size_t)(960 << 10));    // 400,000 B
    uint32_t* ebuf = (uint32_t*)(ws + (size_t)(1400 << 10));// 6.4 MB
    int*      ssrc = (int*)(ws + (size_t)(1400 << 10) + (size_t)(7 << 20)); // 6.4 MB
    short* w0hi = (short*)(ws + (size_t)(16 << 20));
    short* w0lo = w0hi + 32768;
    short* w1hi = w0lo + 32768;
    short* w1lo = w1hi + 32768;
    short* w2hi = w1lo + 32768;
    short* w2lo = w2hi + 16384;                             // ends ~16.3 MB
    ushort* Ybf = (ushort*)(ws + (size_t)(18 << 20));       // 25.6 MB -> ends 43.6
    ushort* Zbf = (ushort*)(ws + (size_t)(44 << 20));       // 25.6 MB -> ends 69.6 (also fp32 z2)
    ushort* Hbf = (ushort*)(ws + (size_t)(70 << 20));       // 25.6 MB -> ends 95.6

    const int* srcp = ei;
    const int* dstp = ei + N_EDGES;

    hist_kernel<<<HB, 256, 0, stream>>>(dstp, H);
    scanbase_kernel<<<1, 256, 0, stream>>>(H, boff);
    scatter_kernel<<<HB, 256, 0, stream>>>(srcp, dstp, H, ebuf);
    bucket_csr<<<NCB, 256, 0, stream>>>(ebuf, boff, off, dinv, ssrc);

    wfrag_kernel<<<16, 256, 0, stream>>>(Wl0, Wr0, 128, 16, 4096, w0hi, w0lo);
    wfrag_kernel<<<16, 256, 0, stream>>>(Wl1, Wr1, 128, 16, 4096, w1hi, w1lo);
    wfrag_kernel<<<8, 256, 0, stream>>>(Wl2, Wr2, 64, 8, 2048, w2hi, w2lo);

    int ggrid = (N_NODES + 63) / 64;   // 1563

    // layer 0: fp32 x -> 3-term split GEMM -> bf16 y,z
    gemm_f32<128, 128><<<ggrid, 256, 0, stream>>>(x, w0hi, w0lo, bl0, Ybf, Zbf);
    agg_wave<128, false><<<NBK, 256, 0, stream>>>(Ybf, Zbf, off, ssrc, dinv, Hbf);

    // layer 1: bf16 h -> 2-term GEMM -> bf16 y,z
    gemm_bf16<128, 128, false><<<ggrid, 256, 0, stream>>>(Hbf, w1hi, w1lo, bl1, Ybf, Zbf);
    agg_wave<128, false><<<NBK, 256, 0, stream>>>(Ybf, Zbf, off, ssrc, dinv, Hbf);

    // layer 2: bf16 h -> 2-term GEMM -> bf16 y2, fp32 z2; final agg to fp32 out
    gemm_bf16<64, 64, true><<<ggrid, 256, 0, stream>>>(Hbf, w2hi, w2lo, bl2, Ybf, (void*)Zbf);
    agg_wave<64, true><<<NBK, 256, 0, stream>>>(Ybf, (const void*)Zbf, off, ssrc, dinv, out);
}

// Round 13
// 326.730 us; speedup vs baseline: 1.1107x; 1.0095x over previous
//
#include <hip/hip_runtime.h>
#include <cstdint>

#define N_NODES 100000
#define N_EDGES 1600000

constexpr int NCB = 196;   // coarse buckets: dst >> 9 (512 nodes each)
constexpr int HB  = 391;   // binning blocks, 4096 edges each
constexpr int NBK = N_NODES / 4; // 25000 agg blocks (4 nodes/block)

typedef __attribute__((ext_vector_type(8))) short short8;
typedef __attribute__((ext_vector_type(4))) float f32x4;

__device__ inline uint32_t fbits(float f) { union { float f; uint32_t u; } c; c.f = f; return c.u; }
__device__ inline float bfloat(uint32_t u) { union { uint32_t u; float f; } c; c.u = u; return c.f; }

__device__ inline void bsplit(float a, short& hi, short& lo) {
    uint32_t h = fbits(a) & 0xFFFF0000u;
    float fl = a - bfloat(h);
    hi = (short)(h >> 16);
    lo = (short)(fbits(fl) >> 16);
}

__device__ inline ushort f2bf(float f) { // RNE fp32->bf16
    uint32_t u = fbits(f);
    return (ushort)((u + 0x7FFFu + ((u >> 16) & 1u)) >> 16);
}

// bf16-pair accumulate (proven unpack path)
__device__ inline void acc_word(uint32_t w, float& lo, float& hi) {
    lo += bfloat(w << 16);
    hi += bfloat(w & 0xFFFF0000u);
}

// ---------------- binning: hist -> scan/bases -> scatter ----------------

__global__ __launch_bounds__(256)
void hist_kernel(const int* __restrict__ dst, int* __restrict__ H) {
    __shared__ int h[NCB];
    for (int i = threadIdx.x; i < NCB; i += 256) h[i] = 0;
    __syncthreads();
    int e0 = blockIdx.x * 4096;
    #pragma unroll
    for (int it = 0; it < 16; ++it) {
        int e = e0 + it * 256 + threadIdx.x;
        if (e < N_EDGES) atomicAdd(&h[dst[e] >> 9], 1);
    }
    __syncthreads();
    for (int i = threadIdx.x; i < NCB; i += 256) H[blockIdx.x * NCB + i] = h[i];
}

__global__ __launch_bounds__(256)
void scanbase_kernel(int* __restrict__ H, int* __restrict__ boff) {
    __shared__ int tot[NCB];
    __shared__ int base[NCB + 1];
    int j = threadIdx.x;
    if (j < NCB) {
        int s = 0;
        for (int b = 0; b < HB; ++b) s += H[b * NCB + j];
        tot[j] = s;
    }
    __syncthreads();
    if (j == 0) {
        int run = 0;
        for (int k = 0; k < NCB; ++k) { base[k] = run; run += tot[k]; }
        base[NCB] = run;
    }
    __syncthreads();
    if (j <= NCB) boff[j] = base[j];
    if (j < NCB) {
        int run = base[j];
        for (int b = 0; b < HB; ++b) {
            int v = H[b * NCB + j];
            H[b * NCB + j] = run;
            run += v;
        }
    }
}

__global__ __launch_bounds__(256)
void scatter_kernel(const int* __restrict__ src, const int* __restrict__ dst,
                    const int* __restrict__ H, uint32_t* __restrict__ ebuf) {
    __shared__ int cur[NCB];
    for (int i = threadIdx.x; i < NCB; i += 256) cur[i] = H[blockIdx.x * NCB + i];
    __syncthreads();
    int e0 = blockIdx.x * 4096;
    #pragma unroll
    for (int it = 0; it < 16; ++it) {
        int e = e0 + it * 256 + threadIdx.x;
        if (e < N_EDGES) {
            int d = dst[e];
            int p = atomicAdd(&cur[d >> 9], 1);
            ebuf[p] = ((uint32_t)src[e] << 9) | (uint32_t)(d & 511);
        }
    }
}

// ---------------- bucket -> exact CSR ----------------

__global__ __launch_bounds__(256)
void bucket_csr(const uint32_t* __restrict__ ebuf, const int* __restrict__ boff,
                int* __restrict__ off, float* __restrict__ dinv,
                int* __restrict__ ssrc) {
    __shared__ int deg[512];
    __shared__ int cur[512];
    __shared__ int wsum[4];
    int t = threadIdx.x, lane = t & 63, w = t >> 6;
    int j = blockIdx.x;
    int base = boff[j], end = boff[j + 1];
    int node0 = j << 9;

    deg[t] = 0; deg[t + 256] = 0;
    __syncthreads();

    for (int p = base + t; p < end; p += 256)
        atomicAdd(&deg[ebuf[p] & 511u], 1);
    __syncthreads();

    int d0 = deg[2 * t], d1 = deg[2 * t + 1];
    int s = d0 + d1;
    int incl = s;
    #pragma unroll
    for (int d = 1; d < 64; d <<= 1) {
        int u = __shfl_up(incl, d);
        if (lane >= d) incl += u;
    }
    if (lane == 63) wsum[w] = incl;
    __syncthreads();
    if (t < 4) {
        int v = wsum[t];
        int iv = v;
        #pragma unroll
        for (int d = 1; d < 4; d <<= 1) {
            int u = __shfl_up(iv, d, 4);
            if (t >= d) iv += u;
        }
        wsum[t] = iv - v;
    }
    __syncthreads();
    int ebase = wsum[w] + (incl - s);
    cur[2 * t] = ebase;
    cur[2 * t + 1] = ebase + d0;
    int n0 = node0 + 2 * t, n1 = n0 + 1;
    if (n0 < N_NODES) {
        off[n0] = base + ebase;
        dinv[n0] = 1.0f / (float)max(d0, 1);
    }
    if (n1 < N_NODES) {
        off[n1] = base + ebase + d0;
        dinv[n1] = 1.0f / (float)max(d1, 1);
    }
    if (j == 0 && t == 0) off[N_NODES] = N_EDGES;
    __syncthreads();

    for (int p = base + t; p < end; p += 256) {
        uint32_t ent = ebuf[p];
        int pos = atomicAdd(&cur[ent & 511u], 1);
        ssrc[base + pos] = (int)(ent >> 9);
    }
}

// ---------------- W pre-split into MFMA fragment order ----------------

__global__ void wfrag_kernel(const float* __restrict__ W1, const float* __restrict__ W2,
                             int C1, int NCT, int ntask,
                             short* __restrict__ fhi, short* __restrict__ flo) {
    int tau = blockIdx.x * 256 + threadIdx.x;
    if (tau >= ntask) return;
    int lane = tau & 63;
    int ct = (tau >> 6) % NCT;
    int ks = (tau >> 6) / NCT;
    int col = ct * 16 + (lane & 15);
    int k = ks * 32 + (lane >> 4) * 8;
    const float* p = (col < C1) ? &W1[(size_t)col * 128 + k]
                                : &W2[(size_t)(col - C1) * 128 + k];
    short8 h8, l8;
    #pragma unroll
    for (int j = 0; j < 8; ++j) {
        short h, l;
        bsplit(p[j], h, l);
        h8[j] = h; l8[j] = l;
    }
    *reinterpret_cast<short8*>(&fhi[(size_t)tau * 8]) = h8;
    *reinterpret_cast<short8*>(&flo[(size_t)tau * 8]) = l8;
}

// ---------------- MFMA GEMM, fp32 A (3-term split), bf16 outs via LDS — layer 0 ----------------

template<int C1, int C2>
__global__ __launch_bounds__(256)
void gemm_f32(const float* __restrict__ H, const short* __restrict__ Wfhi,
              const short* __restrict__ Wflo, const float* __restrict__ bias2,
              ushort* __restrict__ out1, ushort* __restrict__ out2) {
    constexpr int COUT = C1 + C2;       // 256
    constexpr int CT = COUT / 64;
    constexpr int NCT = COUT / 16;
    __shared__ short smem[16384];       // Ahi|Alo (32KB), re-aliased as C-tile
    short* Ahi = smem;
    short* Alo = smem + 8192;
    int t = threadIdx.x;
    int l = t & 63, w = t >> 6;
    int lr = l & 15, kg = l >> 4;
    int r0 = blockIdx.x * 64;
    int c_base = w * (COUT / 4);
    const bool is1 = (c_base < C1);

    #pragma unroll
    for (int it = 0; it < 4; ++it) {
        int lin = t + it * 256;
        int row = lin >> 4, ch = lin & 15;
        float av[8];
        if (r0 + row < N_NODES) {
            const float* p = &H[(size_t)(r0 + row) * 128 + ch * 8];
            float4 v0 = *reinterpret_cast<const float4*>(p);
            float4 v1 = *reinterpret_cast<const float4*>(p + 4);
            av[0] = v0.x; av[1] = v0.y; av[2] = v0.z; av[3] = v0.w;
            av[4] = v1.x; av[5] = v1.y; av[6] = v1.z; av[7] = v1.w;
        } else {
            #pragma unroll
            for (int j = 0; j < 8; ++j) av[j] = 0.f;
        }
        short8 h8, l8;
        #pragma unroll
        for (int j = 0; j < 8; ++j) {
            short h, lo2;
            bsplit(av[j], h, lo2);
            h8[j] = h; l8[j] = lo2;
        }
        int off = row * 128 + ((ch ^ (row & 7)) << 3);
        *reinterpret_cast<short8*>(&Ahi[off]) = h8;
        *reinterpret_cast<short8*>(&Alo[off]) = l8;
    }
    __syncthreads();

    f32x4 acc[4][CT];
    #pragma unroll
    for (int m = 0; m < 4; ++m)
        #pragma unroll
        for (int c = 0; c < CT; ++c)
            acc[m][c] = (f32x4){0.f, 0.f, 0.f, 0.f};

    #pragma unroll
    for (int ks = 0; ks < 4; ++ks) {
        int ch = ks * 4 + kg;
        short8 ahi[4], alo[4];
        #pragma unroll
        for (int m = 0; m < 4; ++m) {
            int row = m * 16 + lr;
            int off = row * 128 + ((ch ^ (row & 7)) << 3);
            ahi[m] = *reinterpret_cast<const short8*>(&Ahi[off]);
            alo[m] = *reinterpret_cast<const short8*>(&Alo[off]);
        }
        short8 bhi[CT], blo[CT];
        #pragma unroll
        for (int c = 0; c < CT; ++c) {
            int ctg = w * CT + c;
            size_t fo = ((size_t)(ks * NCT + ctg) * 64 + l) * 8;
            bhi[c] = *reinterpret_cast<const short8*>(&Wfhi[fo]);
            blo[c] = *reinterpret_cast<const short8*>(&Wflo[fo]);
        }
        #pragma unroll
        for (int m = 0; m < 4; ++m)
            #pragma unroll
            for (int c = 0; c < CT; ++c) {
                acc[m][c] = __builtin_amdgcn_mfma_f32_16x16x32_bf16(ahi[m], bhi[c], acc[m][c], 0, 0, 0);
                acc[m][c] = __builtin_amdgcn_mfma_f32_16x16x32_bf16(ahi[m], blo[c], acc[m][c], 0, 0, 0);
                acc[m][c] = __builtin_amdgcn_mfma_f32_16x16x32_bf16(alo[m], bhi[c], acc[m][c], 0, 0, 0);
            }
    }

    // epilogue: swizzled LDS C-tile -> coalesced uint4 stores
    float bb[CT];
    #pragma unroll
    for (int c = 0; c < CT; ++c) {
        int colg = c_base + c * 16 + lr;
        bb[c] = is1 ? 0.f : bias2[colg - C1];
    }
    __syncthreads();
    ushort* Ct = (ushort*)smem;         // [64][256], 32B-seg swizzle: seg ^ ((row>>2)&3)
    #pragma unroll
    for (int c = 0; c < CT; ++c) {
        int seg = c_base / 16 + c;
        #pragma unroll
        for (int m = 0; m < 4; ++m)
            #pragma unroll
            for (int r = 0; r < 4; ++r) {
                int row = m * 16 + kg * 4 + r;
                int sw = seg ^ ((row >> 2) & 3);
                Ct[row * 256 + sw * 16 + lr] = f2bf(acc[m][c][r] + bb[c]);
            }
    }
    __syncthreads();
    #pragma unroll
    for (int it = 0; it < 8; ++it) {
        int lin = it * 256 + t;
        int row = lin >> 5, chk = lin & 31;
        int grow = r0 + row;
        if (grow < N_NODES) {
            int sw = (chk >> 1) ^ ((row >> 2) & 3);
            uint4 v = *reinterpret_cast<const uint4*>(&Ct[row * 256 + sw * 16 + (chk & 1) * 8]);
            if (chk < 16)
                *reinterpret_cast<uint4*>(&out1[(size_t)grow * C1 + chk * 8]) = v;
            else
                *reinterpret_cast<uint4*>(&out2[(size_t)grow * C2 + (chk - 16) * 8]) = v;
        }
    }
}

// ---------------- MFMA GEMM, bf16 A (2-term) — layers 1,2 ----------------

template<int C1, int C2, bool ZF32>
__global__ __launch_bounds__(256)
void gemm_bf16(const ushort* __restrict__ H, const short* __restrict__ Wfhi,
               const short* __restrict__ Wflo, const float* __restrict__ bias2,
               ushort* __restrict__ out1, void* __restrict__ out2v) {
    constexpr int COUT = C1 + C2;
    constexpr int CT = COUT / 64;
    constexpr int NCT = COUT / 16;
    constexpr int SMEM = ZF32 ? 8192 : (64 * COUT > 8192 ? 64 * COUT : 8192);
    __shared__ short smem[SMEM];
    short* A = smem;
    int t = threadIdx.x;
    int l = t & 63, w = t >> 6;
    int lr = l & 15, kg = l >> 4;
    int r0 = blockIdx.x * 64;
    int c_base = w * (COUT / 4);
    const bool is1 = (c_base < C1);

    #pragma unroll
    for (int it = 0; it < 4; ++it) {
        int lin = t + it * 256;
        int row = lin >> 4, ch = lin & 15;
        short8 v = (short8){0, 0, 0, 0, 0, 0, 0, 0};
        if (r0 + row < N_NODES)
            v = *reinterpret_cast<const short8*>(&H[(size_t)(r0 + row) * 128 + ch * 8]);
        int off = row * 128 + ((ch ^ (row & 7)) << 3);
        *reinterpret_cast<short8*>(&A[off]) = v;
    }
    __syncthreads();

    f32x4 acc[4][CT];
    #pragma unroll
    for (int m = 0; m < 4; ++m)
        #pragma unroll
        for (int c = 0; c < CT; ++c)
            acc[m][c] = (f32x4){0.f, 0.f, 0.f, 0.f};

    #pragma unroll
    for (int ks = 0; ks < 4; ++ks) {
        int ch = ks * 4 + kg;
        short8 a[4];
        #pragma unroll
        for (int m = 0; m < 4; ++m) {
            int row = m * 16 + lr;
            int off = row * 128 + ((ch ^ (row & 7)) << 3);
            a[m] = *reinterpret_cast<const short8*>(&A[off]);
        }
        short8 bhi[CT], blo[CT];
        #pragma unroll
        for (int c = 0; c < CT; ++c) {
            int ctg = w * CT + c;
            size_t fo = ((size_t)(ks * NCT + ctg) * 64 + l) * 8;
            bhi[c] = *reinterpret_cast<const short8*>(&Wfhi[fo]);
            blo[c] = *reinterpret_cast<const short8*>(&Wflo[fo]);
        }
        #pragma unroll
        for (int m = 0; m < 4; ++m)
            #pragma unroll
            for (int c = 0; c < CT; ++c) {
                acc[m][c] = __builtin_amdgcn_mfma_f32_16x16x32_bf16(a[m], bhi[c], acc[m][c], 0, 0, 0);
                acc[m][c] = __builtin_amdgcn_mfma_f32_16x16x32_bf16(a[m], blo[c], acc[m][c], 0, 0, 0);
            }
    }

    if (!ZF32) {
        float bb[CT];
        #pragma unroll
        for (int c = 0; c < CT; ++c) {
            int colg = c_base + c * 16 + lr;
            bb[c] = is1 ? 0.f : bias2[colg - C1];
        }
        __syncthreads();
        ushort* Ct = (ushort*)smem;
        #pragma unroll
        for (int c = 0; c < CT; ++c) {
            int seg = c_base / 16 + c;
            #pragma unroll
            for (int m = 0; m < 4; ++m)
                #pragma unroll
                for (int r = 0; r < 4; ++r) {
                    int row = m * 16 + kg * 4 + r;
                    int sw = seg ^ ((row >> 2) & 3);
                    Ct[row * COUT + sw * 16 + lr] = f2bf(acc[m][c][r] + bb[c]);
                }
        }
        __syncthreads();
        constexpr int CHR = COUT / 8;
        #pragma unroll
        for (int it = 0; it < 64 * CHR / 256; ++it) {
            int lin = it * 256 + t;
            int row = lin / CHR, chk = lin % CHR;
            int grow = r0 + row;
            if (grow < N_NODES) {
                int sw = (chk >> 1) ^ ((row >> 2) & 3);
                uint4 v = *reinterpret_cast<const uint4*>(&Ct[row * COUT + sw * 16 + (chk & 1) * 8]);
                if (chk < C1 / 8)
                    *reinterpret_cast<uint4*>(&out1[(size_t)grow * C1 + chk * 8]) = v;
                else
                    *reinterpret_cast<uint4*>(&((ushort*)out2v)[(size_t)grow * C2 + (chk - C1 / 8) * 8]) = v;
            }
        }
    } else {
        __syncthreads();
        ushort* Yt = (ushort*)smem;     // [64][C1]
        if (is1) {
            #pragma unroll
            for (int c = 0; c < CT; ++c) {
                int seg = c_base / 16 + c;
                #pragma unroll
                for (int m = 0; m < 4; ++m)
                    #pragma unroll
                    for (int r = 0; r < 4; ++r) {
                        int row = m * 16 + kg * 4 + r;
                        int sw = seg ^ ((row >> 2) & 3);
                        Yt[row * C1 + sw * 16 + lr] = f2bf(acc[m][c][r]);
                    }
            }
        } else {
            float* out2 = (float*)out2v;
            #pragma unroll
            for (int c = 0; c < CT; ++c) {
                int col = c_base - C1 + c * 16 + lr;
                float bbv = bias2[col];
                #pragma unroll
                for (int m = 0; m < 4; ++m)
                    #pragma unroll
                    for (int r = 0; r < 4; ++r) {
                        int row = r0 + m * 16 + kg * 4 + r;
                        if (row < N_NODES)
                            out2[(size_t)row * C2 + col] = acc[m][c][r] + bbv;
                    }
            }
        }
        __syncthreads();
        constexpr int CHR = C1 / 8;
        #pragma unroll
        for (int it = 0; it < 64 * CHR / 256; ++it) {
            int lin = it * 256 + t;
            int row = lin / CHR, chk = lin % CHR;
            int grow = r0 + row;
            if (grow < N_NODES) {
                int sw = (chk >> 1) ^ ((row >> 2) & 3);
                uint4 v = *reinterpret_cast<const uint4*>(&Yt[row * C1 + sw * 16 + (chk & 1) * 8]);
                *reinterpret_cast<uint4*>(&out1[(size_t)grow * C1 + chk * 8]) = v;
            }
        }
    }
}

// ---------------- wave-per-node aggregation, full-row, depth-4 pipelined ----------------
// One wave per node; lanes = (chunk = l % NCH, eslot = l / NCH).
// Depth-4: 4 uint4 batches in flight = 16 (C=128) / 32 (C=64) edges — covers mean deg 16.
// FINAL=false: Z bf16, out bf16 + relu.  FINAL=true: Z fp32, out fp32, no relu.

template<int C, bool FINAL>
__global__ __launch_bounds__(256)
void agg_wave(const ushort* __restrict__ Y, const void* __restrict__ Zv,
              const int* __restrict__ off, const int* __restrict__ ssrc,
              const float* __restrict__ dinv, void* __restrict__ outv) {
    constexpr int NCH = C / 8;       // 16B chunks per row: 16 (C=128) / 8 (C=64)
    constexpr int ESL = 64 / NCH;    // parallel edge slots: 4 / 8
    int t = threadIdx.x, l = t & 63;
    int i = blockIdx.x * 4 + (t >> 6);
    int chunk = l & (NCH - 1);
    int eslot = l / NCH;
    const char* Yb = (const char*)(Y + chunk * 8);

    int p0 = off[i], p1 = off[i + 1];
    float acc[8] = {0.f, 0.f, 0.f, 0.f, 0.f, 0.f, 0.f, 0.f};

    #define LDQ(q, v, a)  { a = (q) < p1; if (a) { uint32_t s_ = (uint32_t)ssrc[q]; \
        v = *reinterpret_cast<const uint4*>(Yb + s_ * (C * 2)); } }
    #define ACCU(v) { acc_word(v.x, acc[0], acc[1]); acc_word(v.y, acc[2], acc[3]); \
                      acc_word(v.z, acc[4], acc[5]); acc_word(v.w, acc[6], acc[7]); }

    uint4 c0, c1, c2, c3;
    bool a0, a1, a2, a3;
    LDQ(p0 + eslot, c0, a0)
    LDQ(p0 + ESL + eslot, c1, a1)
    LDQ(p0 + 2 * ESL + eslot, c2, a2)
    LDQ(p0 + 3 * ESL + eslot, c3, a3)
    for (int p = p0 + 4 * ESL; p < p1; p += 4 * ESL) {
        uint4 n0, n1, n2, n3;
        bool b0, b1, b2, b3;
        LDQ(p + eslot, n0, b0)
        LDQ(p + ESL + eslot, n1, b1)
        LDQ(p + 2 * ESL + eslot, n2, b2)
        LDQ(p + 3 * ESL + eslot, n3, b3)
        if (a0) ACCU(c0)
        if (a1) ACCU(c1)
        if (a2) ACCU(c2)
        if (a3) ACCU(c3)
        c0 = n0; c1 = n1; c2 = n2; c3 = n3;
        a0 = b0; a1 = b1; a2 = b2; a3 = b3;
    }
    if (a0) ACCU(c0)
    if (a1) ACCU(c1)
    if (a2) ACCU(c2)
    if (a3) ACCU(c3)
    #undef LDQ
    #undef ACCU

    #pragma unroll
    for (int d = NCH; d < 64; d <<= 1)
        #pragma unroll
        for (int j = 0; j < 8; ++j)
            acc[j] += __shfl_xor(acc[j], d);

    if (eslot == 0) {
        float di = dinv[i];
        size_t eo = (size_t)i * C + chunk * 8;
        float zz[8];
        if (FINAL) {
            const float* zp = (const float*)Zv + eo;
            float4 z0 = *reinterpret_cast<const float4*>(zp);
            float4 z1 = *reinterpret_cast<const float4*>(zp + 4);
            zz[0] = z0.x; zz[1] = z0.y; zz[2] = z0.z; zz[3] = z0.w;
            zz[4] = z1.x; zz[5] = z1.y; zz[6] = z1.z; zz[7] = z1.w;
        } else {
            uint4 zv = *reinterpret_cast<const uint4*>((const ushort*)Zv + eo);
            uint32_t wd[4] = {zv.x, zv.y, zv.z, zv.w};
            #pragma unroll
            for (int j = 0; j < 4; ++j) {
                zz[2 * j]     = bfloat(wd[j] << 16);
                zz[2 * j + 1] = bfloat(wd[j] & 0xFFFF0000u);
            }
        }
        float r[8];
        #pragma unroll
        for (int j = 0; j < 8; ++j) {
            r[j] = acc[j] * di + zz[j];
            if (!FINAL) r[j] = fmaxf(r[j], 0.f);
        }
        if (FINAL) {
            float* op = (float*)outv + eo;
            *reinterpret_cast<float4*>(op)     = make_float4(r[0], r[1], r[2], r[3]);
            *reinterpret_cast<float4*>(op + 4) = make_float4(r[4], r[5], r[6], r[7]);
        } else {
            uint4 o;
            o.x = (uint32_t)f2bf(r[0]) | ((uint32_t)f2bf(r[1]) << 16);
            o.y = (uint32_t)f2bf(r[2]) | ((uint32_t)f2bf(r[3]) << 16);
            o.z = (uint32_t)f2bf(r[4]) | ((uint32_t)f2bf(r[5]) << 16);
            o.w = (uint32_t)f2bf(r[6]) | ((uint32_t)f2bf(r[7]) << 16);
            *reinterpret_cast<uint4*>((ushort*)outv + eo) = o;
        }
    }
}

// ---------------- launch ----------------

extern "C" void kernel_launch(void* const* d_in, const int* in_sizes, int n_in,
                              void* d_out, int out_size, void* d_ws, size_t ws_size,
                              hipStream_t stream) {
    const float* x   = (const float*)d_in[0];
    const int*   ei  = (const int*)d_in[2];
    const float* Wl0 = (const float*)d_in[3];
    const float* bl0 = (const float*)d_in[4];
    const float* Wr0 = (const float*)d_in[5];
    const float* Wl1 = (const float*)d_in[6];
    const float* bl1 = (const float*)d_in[7];
    const float* Wr1 = (const float*)d_in[8];
    const float* Wl2 = (const float*)d_in[9];
    const float* bl2 = (const float*)d_in[10];
    const float* Wr2 = (const float*)d_in[11];
    float* out = (float*)d_out;

    char* ws = (char*)d_ws;
    int*      H    = (int*)(ws + 0);                        // 306,544 B
    int*      boff = (int*)(ws + (size_t)(384 << 10));      // 788 B
    int*      off  = (int*)(ws + (size_t)(512 << 10));      // 400,004 B
    float*    dinv = (float*)(ws + (size_t)(960 << 10));    // 400,000 B
    uint32_t* ebuf = (uint32_t*)(ws + (size_t)(1400 << 10));// 6.4 MB
    int*      ssrc = (int*)(ws + (size_t)(1400 << 10) + (size_t)(7 << 20)); // 6.4 MB
    short* w0hi = (short*)(ws + (size_t)(16 << 20));
    short* w0lo = w0hi + 32768;
    short* w1hi = w0lo + 32768;
    short* w1lo = w1hi + 32768;
    short* w2hi = w1lo + 32768;
    short* w2lo = w2hi + 16384;                             // ends ~16.3 MB
    ushort* Ybf = (ushort*)(ws + (size_t)(18 << 20));       // 25.6 MB -> ends 43.6
    ushort* Zbf = (ushort*)(ws + (size_t)(44 << 20));       // 25.6 MB -> ends 69.6 (also fp32 z2)
    ushort* Hbf = (ushort*)(ws + (size_t)(70 << 20));       // 25.6 MB -> ends 95.6

    const int* srcp = ei;
    const int* dstp = ei + N_EDGES;

    hist_kernel<<<HB, 256, 0, stream>>>(dstp, H);
    scanbase_kernel<<<1, 256, 0, stream>>>(H, boff);
    scatter_kernel<<<HB, 256, 0, stream>>>(srcp, dstp, H, ebuf);
    bucket_csr<<<NCB, 256, 0, stream>>>(ebuf, boff, off, dinv, ssrc);

    wfrag_kernel<<<16, 256, 0, stream>>>(Wl0, Wr0, 128, 16, 4096, w0hi, w0lo);
    wfrag_kernel<<<16, 256, 0, stream>>>(Wl1, Wr1, 128, 16, 4096, w1hi, w1lo);
    wfrag_kernel<<<8, 256, 0, stream>>>(Wl2, Wr2, 64, 8, 2048, w2hi, w2lo);

    int ggrid = (N_NODES + 63) / 64;   // 1563

    // layer 0: fp32 x -> 3-term split GEMM -> bf16 y,z
    gemm_f32<128, 128><<<ggrid, 256, 0, stream>>>(x, w0hi, w0lo, bl0, Ybf, Zbf);
    agg_wave<128, false><<<NBK, 256, 0, stream>>>(Ybf, Zbf, off, ssrc, dinv, Hbf);

    // layer 1: bf16 h -> 2-term GEMM -> bf16 y,z
    gemm_bf16<128, 128, false><<<ggrid, 256, 0, stream>>>(Hbf, w1hi, w1lo, bl1, Ybf, Zbf);
    agg_wave<128, false><<<NBK, 256, 0, stream>>>(Ybf, Zbf, off, ssrc, dinv, Hbf);

    // layer 2: bf16 h -> 2-term GEMM -> bf16 y2, fp32 z2; final agg to fp32 out
    gemm_bf16<64, 64, true><<<ggrid, 256, 0, stream>>>(Hbf, w2hi, w2lo, bl2, Ybf, (void*)Zbf);
    agg_wave<64, true><<<NBK, 256, 0, stream>>>(Ybf, (const void*)Zbf, off, ssrc, dinv, out);
}